// Round 1
// 459.556 us; speedup vs baseline: 1.0504x; 1.0504x over previous
//
#include <hip/hip_runtime.h>

#define GAMMA 0.1f

typedef unsigned short u16;
typedef u16 u16x8 __attribute__((ext_vector_type(8)));
typedef short s16x8 __attribute__((ext_vector_type(8)));
typedef float f32x4 __attribute__((ext_vector_type(4)));

__device__ __forceinline__ float b2f(u16 u) {
  return __uint_as_float(((unsigned)u) << 16);
}
__device__ __forceinline__ u16 f2bf(float f) {
  unsigned u = __float_as_uint(f);
  unsigned r = (u + 0x7FFFu + ((u >> 16) & 1u)) >> 16;
  return (u16)r;
}

// async global->LDS, 16B per lane; lds base must be wave-uniform, HW adds lane*16
__device__ __forceinline__ void gl2lds16(const u16* g, u16* l) {
  __builtin_amdgcn_global_load_lds(
      (const __attribute__((address_space(1))) unsigned int*)g,
      (__attribute__((address_space(3))) unsigned int*)l, 16, 0, 0);
}

// XCD-aware bijective swizzle: physical wg p runs on XCD p%8 (round-robin
// dispatch heuristic). logical = (p%8)*(nwg/8) + p/8 gives each XCD a
// CONTIGUOUS logical range, so blocks sharing an A-panel (consecutive
// logical ids, x-fastest) land on the same XCD -> panel is an L2 hit.
// Requires nwg % 8 == 0 (all grids here: 2304/4608/5184).
__device__ __forceinline__ int xcd_swz(int phys, int nwg) {
  return (phys & 7) * (nwg >> 3) + (phys >> 3);
}

// -------- weight transpose + fp32->bf16: dst[n*K + k] = bf16(src[k*N + n]) --
__global__ __launch_bounds__(256) void transpose_k(
    const float* __restrict__ src, u16* __restrict__ dst, int K, int N)
{
  int idx = blockIdx.x * 256 + threadIdx.x;
  if (idx >= K * N) return;
  int nn = idx / K, kk = idx - nn * K;
  dst[idx] = f2bf(src[kk * N + nn]);
}

// -------- bias concat (fp32 passthrough) --------
__global__ __launch_bounds__(256) void bias_kernel(
    const float* __restrict__ bq, const float* __restrict__ bk,
    const float* __restrict__ bv, const float* __restrict__ bp1,
    const float* __restrict__ bo,
    float* __restrict__ biasQ, float* __restrict__ biasKVP,
    float* __restrict__ biasO)
{
  int i = blockIdx.x * 256 + threadIdx.x;
  if (i < 512) {
    biasQ[i] = bq[i];
  } else if (i < 1664) {
    int j = i - 512;
    float v;
    if (j < 512) v = bk[j];
    else if (j < 1024) v = bv[j - 512];
    else v = bp1[j - 1024];
    biasKVP[j] = v;
  } else if (i < 2176) {
    biasO[i - 1664] = bo[i - 1664];
  }
}

// -------- GEMM with gather-from-h A operand (A fp32 -> bf16 in staging) -----
// h layout: (bt=64, k=512, s=576) fp32. C: 36864 rows x NC bf16,
// row = (b*576+s)*16+t. WT: NC rows x 512 bf16 (k contiguous).
// Tile: BM=64 (s), BN=128 (cols), BK=32.
// A LDS layout: addr(row,k) = row*32 + ((k>>3) ^ ((row>>3)&3))*8 + (k&7)
//   -> scalar transpose writes are ~2-way (free); b128 reads are min-phase.
// B staged via global_load_lds (LDB=32, lane-linear).
__global__ __launch_bounds__(256) void gemm_gather(
    const float* __restrict__ h, const u16* __restrict__ WT,
    const float* __restrict__ bias, u16* __restrict__ C, int NC)
{
  __shared__ __align__(16) u16 Al[64 * 32];
  __shared__ __align__(16) u16 Bl[128 * 32];
  const int tid = threadIdx.x;
  const int w = tid >> 6, lane = tid & 63;
  const int lhi = lane >> 4, llo = lane & 15;

  // XCD swizzle: colocate the gridDim.x blocks sharing one A-panel
  const int nwg = gridDim.x * gridDim.y;
  const int phys = blockIdx.y * gridDim.x + blockIdx.x;
  const int logical = xcd_swz(phys, nwg);
  const int bx = logical % gridDim.x;
  const int y = logical / gridDim.x;

  const int bt = y / 9, stile = y - bt * 9;
  const int s0 = stile * 64;
  const int col0 = bx * 128;

  const float* Ab = h + (size_t)bt * (512 * 576) + s0;
  const u16* Bb = WT + (size_t)col0 * 512;

  const int ak = tid >> 3;          // 0..31 : k within tile
  const int aso = (tid & 7) * 8;    // s row base
  const int ae = ak & 7;            // element within 8-chunk
  const int ac = ak >> 3;           // chunk (wave-uniform)

  // B stage addressing (per wave: 2 calls of 1024B)
  const int q0 = w * 2, q1 = w * 2 + 1;
  const int bko = (lane & 3) * 8;
  const int br0 = q0 * 16 + (lane >> 2);
  const int br1 = q1 * 16 + (lane >> 2);

  f32x4 acc[4][2];
#pragma unroll
  for (int mi = 0; mi < 4; ++mi)
#pragma unroll
    for (int ni = 0; ni < 2; ++ni)
#pragma unroll
      for (int e = 0; e < 4; ++e) acc[mi][ni][e] = 0.f;

  for (int kt = 0; kt < 16; ++kt) {
    __syncthreads();
    // B: async direct-to-LDS
    gl2lds16(Bb + (size_t)br0 * 512 + kt * 32 + bko, &Bl[q0 * 512]);
    gl2lds16(Bb + (size_t)br1 * 512 + kt * 32 + bko, &Bl[q1 * 512]);
    // A: coalesced fp32 loads, swizzled bf16 transpose into LDS
    const float* ap = Ab + (size_t)(kt * 32 + ak) * 576 + aso;
    float4 a0 = *(const float4*)ap;
    float4 a1 = *(const float4*)(ap + 4);
    float av[8] = {a0.x, a0.y, a0.z, a0.w, a1.x, a1.y, a1.z, a1.w};
#pragma unroll
    for (int i = 0; i < 8; ++i) {
      int row = aso + i;
      int cs = ac ^ ((row >> 3) & 3);
      Al[row * 32 + cs * 8 + ae] = f2bf(av[i]);
    }
    __syncthreads();

    s16x8 af[4], bfr[2];
#pragma unroll
    for (int mi = 0; mi < 4; ++mi) {
      int row = mi * 16 + llo;
      int cs = lhi ^ ((row >> 3) & 3);
      af[mi] = *(const s16x8*)&Al[row * 32 + cs * 8];
    }
#pragma unroll
    for (int ni = 0; ni < 2; ++ni)
      bfr[ni] = *(const s16x8*)&Bl[(w * 32 + ni * 16 + llo) * 32 + lhi * 8];
#pragma unroll
    for (int mi = 0; mi < 4; ++mi)
#pragma unroll
      for (int ni = 0; ni < 2; ++ni)
        acc[mi][ni] = __builtin_amdgcn_mfma_f32_16x16x32_bf16(
            af[mi], bfr[ni], acc[mi][ni], 0, 0, 0);
  }

  const int b_ = bt >> 4, t_ = bt & 15;
  const size_t rowbase = (size_t)(b_ * 576 + s0) * 16 + t_;
  float bia0 = bias[col0 + w * 32 + llo];
  float bia1 = bias[col0 + w * 32 + 16 + llo];
#pragma unroll
  for (int mi = 0; mi < 4; ++mi) {
#pragma unroll
    for (int i = 0; i < 4; ++i) {
      const int m = mi * 16 + lhi * 4 + i;
      u16* cp = C + (rowbase + (size_t)m * 16) * NC + col0 + w * 32 + llo;
      cp[0]  = f2bf(acc[mi][0][i] + bia0);
      cp[16] = f2bf(acc[mi][1][i] + bia1);
    }
  }
}

// -------- penalty MLP tail: gelu -> dot(Wp2) -> sigmoid, one wave per row ----
__global__ __launch_bounds__(256) void pviol_kernel(
    const u16* __restrict__ KVP, const float* __restrict__ Wp2,
    const float* __restrict__ bp2, float* __restrict__ pv)
{
  const int tid = threadIdx.x;
  const int w = tid >> 6, lane = tid & 63;
  const int row = blockIdx.x * 4 + w;
  const int c = lane * 2;
  const u16* hp = KVP + (size_t)row * 1152 + 1024 + c;
  float x0 = b2f(hp[0]), x1 = b2f(hp[1]);
  float g0 = 0.5f * x0 * (1.f + erff(x0 * 0.70710678f));
  float g1 = 0.5f * x1 * (1.f + erff(x1 * 0.70710678f));
  float sum = g0 * Wp2[c] + g1 * Wp2[c + 1];
#pragma unroll
  for (int d = 1; d < 64; d <<= 1) sum += __shfl_xor(sum, d, 64);
  if (lane == 0) {
    float z = sum + bp2[0];
    pv[row] = 1.f / (1.f + expf(-z));
  }
}

// -------- attention: one wave per (n, head). att aliases Q (disjoint per wave).
__global__ __launch_bounds__(256) void attn_kernel(
    const u16* Q, const u16* __restrict__ KVP,
    const float* __restrict__ pviol, u16* att)
{
  __shared__ __align__(16) u16 Kl[4][16 * 72];
  __shared__ __align__(16) u16 Vl[4][16 * 72];
  __shared__ float Pl[4][16 * 17];
  const int tid = threadIdx.x;
  const int w = tid >> 6, lane = tid & 63;
  // XCD swizzle: the 2 blocks sharing one n's K/V panel become neighbors
  const int logical = xcd_swz(blockIdx.x, gridDim.x);
  const int wid = logical * 4 + w;
  const int n = wid >> 3, hh = wid & 7;
  const int g = lane >> 4, tq = lane & 15;

  // stage K,V 16x64 tiles
  const int r = lane >> 3, co = (lane & 7) * 8;
  const u16* Kb = KVP + (size_t)n * (16 * 1152) + hh * 64;
#pragma unroll
  for (int rr = 0; rr < 2; ++rr) {
    int row = r + rr * 8;
    *(u16x8*)&Kl[w][row * 72 + co] = *(const u16x8*)(Kb + row * 1152 + co);
    *(u16x8*)&Vl[w][row * 72 + co] = *(const u16x8*)(Kb + 512 + row * 1152 + co);
  }
  __syncthreads();

  // scores: lane (g,tq) computes s[tq][g*4+i]
  float s[4] = {0.f, 0.f, 0.f, 0.f};
  const u16* Qr = Q + ((size_t)n * 16 + tq) * 512 + hh * 64;
  for (int kc = 0; kc < 8; ++kc) {
    u16x8 q8 = *(const u16x8*)(Qr + kc * 8);
    float qf[8];
#pragma unroll
    for (int j = 0; j < 8; ++j) qf[j] = b2f(q8[j]);
#pragma unroll
    for (int i = 0; i < 4; ++i) {
      u16x8 k8 = *(const u16x8*)&Kl[w][(g * 4 + i) * 72 + kc * 8];
#pragma unroll
      for (int j = 0; j < 8; ++j) s[i] += qf[j] * b2f(k8[j]);
    }
  }

  const float* pv = pviol + n * 16;
#pragma unroll
  for (int i = 0; i < 4; ++i) s[i] = s[i] * 0.125f - GAMMA * pv[g * 4 + i];

  float mx = fmaxf(fmaxf(s[0], s[1]), fmaxf(s[2], s[3]));
  mx = fmaxf(mx, __shfl_xor(mx, 16, 64));
  mx = fmaxf(mx, __shfl_xor(mx, 32, 64));
  float e[4], sum = 0.f;
#pragma unroll
  for (int i = 0; i < 4; ++i) { e[i] = expf(s[i] - mx); sum += e[i]; }
  sum += __shfl_xor(sum, 16, 64);
  sum += __shfl_xor(sum, 32, 64);
  float inv = 1.f / sum;
#pragma unroll
  for (int i = 0; i < 4; ++i) Pl[w][tq * 17 + g * 4 + i] = e[i] * inv;
  __syncthreads();

  // out[tq][d], d in g*16..g*16+15
  float o[16];
#pragma unroll
  for (int j = 0; j < 16; ++j) o[j] = 0.f;
  for (int tk = 0; tk < 16; ++tk) {
    float p = Pl[w][tq * 17 + tk];
    u16x8 v0 = *(const u16x8*)&Vl[w][tk * 72 + g * 16];
    u16x8 v1 = *(const u16x8*)&Vl[w][tk * 72 + g * 16 + 8];
#pragma unroll
    for (int j = 0; j < 8; ++j) {
      o[j]     += p * b2f(v0[j]);
      o[8 + j] += p * b2f(v1[j]);
    }
  }
  u16* op = att + ((size_t)n * 16 + tq) * 512 + hh * 64 + g * 16;
  u16x8 r0, r1;
#pragma unroll
  for (int j = 0; j < 8; ++j) { r0[j] = f2bf(o[j]); r1[j] = f2bf(o[8 + j]); }
  *(u16x8*)op = r0;
  *(u16x8*)(op + 8) = r1;
}

// -------- output projection: bf16 A (row-major), fp32 out ------------------
// A and B both staged via global_load_lds, LDA=LDB=32 (min-phase b128 reads).
__global__ __launch_bounds__(256) void gemm_out(
    const u16* __restrict__ A, const u16* __restrict__ WT,
    const float* __restrict__ bias, float* __restrict__ out)
{
  __shared__ __align__(16) char smem[128 * 72 * 4];  // >= Al+Bl; Cl fp32 epilogue
  u16* Al = (u16*)smem;                    // 64 x 32
  u16* Bl = (u16*)(smem + 64 * 32 * 2);    // 128 x 32
  const int tid = threadIdx.x;
  const int w = tid >> 6, lane = tid & 63;
  const int lhi = lane >> 4, llo = lane & 15;

  // XCD swizzle: colocate the 4 blocks sharing one A-panel
  const int nwg = gridDim.x * gridDim.y;
  const int phys = blockIdx.y * gridDim.x + blockIdx.x;
  const int logical = xcd_swz(phys, nwg);
  const int bx = logical % gridDim.x;
  const int y = logical / gridDim.x;

  const int bt = y / 9, stile = y - bt * 9;
  const int s0 = stile * 64;
  const int col0 = bx * 128;
  const int b_ = bt >> 4, t_ = bt & 15;

  const u16* Ab = A + ((size_t)(b_ * 576 + s0) * 16 + t_) * 512;
  const u16* Bb = WT + (size_t)col0 * 512;

  // A stage: 1 call/wave (1024B); lane element = w*512 + lane*8
  const int arow = w * 16 + (lane >> 2);   // m row (s index)
  const int ako = (lane & 3) * 8;
  // B stage: 2 calls/wave
  const int q0 = w * 2, q1 = w * 2 + 1;
  const int br0 = q0 * 16 + (lane >> 2);
  const int br1 = q1 * 16 + (lane >> 2);

  f32x4 acc[4][2];
#pragma unroll
  for (int mi = 0; mi < 4; ++mi)
#pragma unroll
    for (int ni = 0; ni < 2; ++ni)
#pragma unroll
      for (int e = 0; e < 4; ++e) acc[mi][ni][e] = 0.f;

  for (int kt = 0; kt < 16; ++kt) {
    __syncthreads();
    gl2lds16(Ab + (size_t)arow * (16 * 512) + kt * 32 + ako, &Al[w * 512]);
    gl2lds16(Bb + (size_t)br0 * 512 + kt * 32 + ako, &Bl[q0 * 512]);
    gl2lds16(Bb + (size_t)br1 * 512 + kt * 32 + ako, &Bl[q1 * 512]);
    __syncthreads();

    s16x8 af[4], bfr[2];
#pragma unroll
    for (int mi = 0; mi < 4; ++mi)
      af[mi] = *(const s16x8*)&Al[(mi * 16 + llo) * 32 + lhi * 8];
#pragma unroll
    for (int ni = 0; ni < 2; ++ni)
      bfr[ni] = *(const s16x8*)&Bl[(w * 32 + ni * 16 + llo) * 32 + lhi * 8];
#pragma unroll
    for (int mi = 0; mi < 4; ++mi)
#pragma unroll
      for (int ni = 0; ni < 2; ++ni)
        acc[mi][ni] = __builtin_amdgcn_mfma_f32_16x16x32_bf16(
            af[mi], bfr[ni], acc[mi][ni], 0, 0, 0);
  }

  __syncthreads();
  float* Cl = (float*)smem;  // 128 (n) x 72 (m, padded) fp32
  float bia0 = bias[col0 + w * 32 + llo];
  float bia1 = bias[col0 + w * 32 + 16 + llo];
#pragma unroll
  for (int mi = 0; mi < 4; ++mi)
#pragma unroll
    for (int i = 0; i < 4; ++i) {
      int m = mi * 16 + lhi * 4 + i;
      Cl[(w * 32 + llo) * 72 + m]      = acc[mi][0][i] + bia0;
      Cl[(w * 32 + 16 + llo) * 72 + m] = acc[mi][1][i] + bia1;
    }
  __syncthreads();
  const int nn = tid >> 1;
  const int mh = (tid & 1) * 32;
  const float* sp = Cl + nn * 72 + mh;
  float* dp = out + ((size_t)bt * 512 + col0 + nn) * 576 + s0 + mh;
#pragma unroll
  for (int j = 0; j < 8; ++j)
    *(float4*)(dp + j * 4) = *(const float4*)(sp + j * 4);
}

extern "C" void kernel_launch(void* const* d_in, const int* in_sizes, int n_in,
                              void* d_out, int out_size, void* d_ws, size_t ws_size,
                              hipStream_t stream)
{
  const float* h_opt = (const float*)d_in[0];
  const float* h_sar = (const float*)d_in[1];
  const float* Wq  = (const float*)d_in[2];
  const float* bq  = (const float*)d_in[3];
  const float* Wk  = (const float*)d_in[4];
  const float* bk  = (const float*)d_in[5];
  const float* Wv  = (const float*)d_in[6];
  const float* bv  = (const float*)d_in[7];
  const float* Wo  = (const float*)d_in[8];
  const float* bo  = (const float*)d_in[9];
  const float* Wp1 = (const float*)d_in[10];
  const float* bp1 = (const float*)d_in[11];
  const float* Wp2 = (const float*)d_in[12];
  const float* bp2 = (const float*)d_in[13];
  float* out = (float*)d_out;

  char* ws = (char*)d_ws;
  u16*   WqT     = (u16*)(ws + 0);          // 512x512 bf16   (524288 B)
  u16*   KVPW    = (u16*)(ws + 524288);     // 1152x512 bf16  (1179648 B)
  u16*   WoT     = (u16*)(ws + 1703936);    // 512x512 bf16   (524288 B)
  float* biasQ   = (float*)(ws + 2228224);  // 512 f32
  float* biasKVP = (float*)(ws + 2230272);  // 1152 f32
  float* biasO   = (float*)(ws + 2234880);  // 512 f32
  float* pviol   = (float*)(ws + 2236928);  // 36864 f32
  u16*   Qbuf    = (u16*)(ws + 2384384);    // 36864x512 bf16  — also att
  u16*   KVPbuf  = (u16*)(ws + 40133120);   // 36864x1152 bf16

  transpose_k<<<1024, 256, 0, stream>>>(Wq, WqT, 512, 512);
  transpose_k<<<1024, 256, 0, stream>>>(Wk, KVPW, 512, 512);
  transpose_k<<<1024, 256, 0, stream>>>(Wv, KVPW + 512 * 512, 512, 512);
  transpose_k<<<256, 256, 0, stream>>>(Wp1, KVPW + 1024 * 512, 512, 128);
  transpose_k<<<1024, 256, 0, stream>>>(Wo, WoT, 512, 512);
  bias_kernel<<<9, 256, 0, stream>>>(bq, bk, bv, bp1, bo, biasQ, biasKVP, biasO);

  gemm_gather<<<dim3(4, 576), 256, 0, stream>>>(h_opt, WqT, biasQ, Qbuf, 512);
  gemm_gather<<<dim3(9, 576), 256, 0, stream>>>(h_sar, KVPW, biasKVP, KVPbuf, 1152);
  pviol_kernel<<<9216, 256, 0, stream>>>(KVPbuf, Wp2, bp2, pviol);
  attn_kernel<<<4608, 256, 0, stream>>>(Qbuf, KVPbuf, pviol, Qbuf);
  gemm_out<<<dim3(4, 576), 256, 0, stream>>>(Qbuf, WoT, biasO, out);
}

// Round 3
// 421.395 us; speedup vs baseline: 1.1455x; 1.0906x over previous
//
#include <hip/hip_runtime.h>

#define GAMMA 0.1f

typedef unsigned short u16;
typedef u16 u16x8 __attribute__((ext_vector_type(8)));
typedef short s16x8 __attribute__((ext_vector_type(8)));
typedef float f32x4 __attribute__((ext_vector_type(4)));
typedef unsigned int ui32x4 __attribute__((ext_vector_type(4)));

__device__ __forceinline__ float b2f(u16 u) {
  return __uint_as_float(((unsigned)u) << 16);
}
__device__ __forceinline__ u16 f2bf(float f) {
  unsigned u = __float_as_uint(f);
  unsigned r = (u + 0x7FFFu + ((u >> 16) & 1u)) >> 16;
  return (u16)r;
}
// pack two f32 -> one u32 holding (bf16(lo) | bf16(hi)<<16)
__device__ __forceinline__ unsigned pk_bf16(float lo, float hi) {
  return (unsigned)f2bf(lo) | ((unsigned)f2bf(hi) << 16);
}

// async global->LDS, 16B per lane; lds base must be wave-uniform, HW adds lane*16
__device__ __forceinline__ void gl2lds16(const u16* g, u16* l) {
  __builtin_amdgcn_global_load_lds(
      (const __attribute__((address_space(1))) unsigned int*)g,
      (__attribute__((address_space(3))) unsigned int*)l, 16, 0, 0);
}

// XCD-aware bijective swizzle (requires nwg % 8 == 0; all grids here qualify)
__device__ __forceinline__ int xcd_swz(int phys, int nwg) {
  return (phys & 7) * (nwg >> 3) + (phys >> 3);
}

// -------- weight transpose + fp32->bf16: dst[n*K + k] = bf16(src[k*N + n]) --
__global__ __launch_bounds__(256) void transpose_k(
    const float* __restrict__ src, u16* __restrict__ dst, int K, int N)
{
  int idx = blockIdx.x * 256 + threadIdx.x;
  if (idx >= K * N) return;
  int nn = idx / K, kk = idx - nn * K;
  dst[idx] = f2bf(src[kk * N + nn]);
}

// -------- bias concat (fp32 passthrough) --------
__global__ __launch_bounds__(256) void bias_kernel(
    const float* __restrict__ bq, const float* __restrict__ bk,
    const float* __restrict__ bv, const float* __restrict__ bp1,
    const float* __restrict__ bo,
    float* __restrict__ biasQ, float* __restrict__ biasKVP,
    float* __restrict__ biasO)
{
  int i = blockIdx.x * 256 + threadIdx.x;
  if (i < 512) {
    biasQ[i] = bq[i];
  } else if (i < 1664) {
    int j = i - 512;
    float v;
    if (j < 512) v = bk[j];
    else if (j < 1024) v = bv[j - 512];
    else v = bp1[j - 1024];
    biasKVP[j] = v;
  } else if (i < 2176) {
    biasO[i - 1664] = bo[i - 1664];
  }
}

// ---------------------------------------------------------------------------
// GEMM with gather-from-h A operand.  h: (bt=64, k=512, s=576) fp32.
// C: 36864 rows x NC bf16, row = (b*576+s)*16+t.  WT: NC rows x 512 bf16.
// Tile: BM=64 (s) x BN=128 (cols) x BK=64, 8 K-steps, 4 waves.
// Per wave per step: 16 MFMA (acc[4][2], two k-halves).
// A: 16 k-strided coalesced dword loads/thread -> pack -> 2 swizzled
//    ds_write_b128 (single-buffered LDS, written between the two barriers).
// B: double-buffered global_load_lds, source pre-swizzled so that
//    LDS[row n][16B-slot s] holds k-octet (s ^ (n&7)) -> conflict-free b128.
// Prefetch: A(kt+1) reg loads + B(kt+1) gl2lds issued at START of compute
// phase kt; the implicit vmcnt(0) at the next iteration's first barrier
// waits on loads that already had a full compute phase in flight.
// ---------------------------------------------------------------------------
__global__ __launch_bounds__(256) void gemm_gather(
    const float* __restrict__ h, const u16* __restrict__ WT,
    const float* __restrict__ bias, u16* __restrict__ C, int NC)
{
  __shared__ __align__(16) u16 Al[64 * 64];        // 8 KB
  __shared__ __align__(16) u16 Bl[2][128 * 64];    // 32 KB
  const int tid = threadIdx.x;
  const int w = tid >> 6, lane = tid & 63;
  const int lhi = lane >> 4, llo = lane & 15;

  const int nwg = gridDim.x * gridDim.y;
  const int phys = blockIdx.y * gridDim.x + blockIdx.x;
  const int logical = xcd_swz(phys, nwg);
  const int bx = logical % gridDim.x;
  const int y = logical / gridDim.x;

  const int bt = y / 9, stile = y - bt * 9;
  const int s0 = stile * 64;
  const int col0 = bx * 128;

  const float* Ab = h + (size_t)bt * (512 * 576) + s0;
  const u16* Bb = WT + (size_t)col0 * 512;

  // A staging map: thread -> s row (0..63), k-octets {w, w+4}
  const int s_a = tid & 63;
  const int c_a = tid >> 6;          // wave id = k-octet (low half)
  const int sw_a = s_a & 7;
  const float* apb = Ab + s_a;

  // B gl2lds: call q covers rows q*8..q*8+7; lane -> row q*8+(l>>3),
  // dest 16B-slot l&7; source k-octet pre-swizzled: (l&7)^(l>>3)
  const int brow = lane >> 3;
  const int bko = ((lane & 7) ^ brow) * 8;

  f32x4 acc[4][2];
#pragma unroll
  for (int mi = 0; mi < 4; ++mi)
#pragma unroll
    for (int ni = 0; ni < 2; ++ni)
#pragma unroll
      for (int e = 0; e < 4; ++e) acc[mi][ni][e] = 0.f;

  float pre[16];
  // prologue: B(0) -> Bl[0], A(0) -> regs
#pragma unroll
  for (int i = 0; i < 4; ++i) {
    int q = w * 4 + i;
    gl2lds16(Bb + (size_t)(q * 8 + brow) * 512 + bko, &Bl[0][q * 512]);
  }
#pragma unroll
  for (int j = 0; j < 8; ++j) pre[j] = apb[(size_t)(c_a * 8 + j) * 576];
#pragma unroll
  for (int j = 0; j < 8; ++j) pre[8 + j] = apb[(size_t)(c_a * 8 + 32 + j) * 576];

  for (int kt = 0; kt < 8; ++kt) {
    // convert A(kt) in regs (waits the prefetched loads via data dep)
    unsigned cw[8];
#pragma unroll
    for (int i = 0; i < 4; ++i) {
      cw[i]     = pk_bf16(pre[2 * i],     pre[2 * i + 1]);
      cw[4 + i] = pk_bf16(pre[8 + 2 * i], pre[9 + 2 * i]);
    }
    __syncthreads();  // (a) prev compute LDS reads done; B(kt) gl2lds drained
    {
      ui32x4 v0 = {cw[0], cw[1], cw[2], cw[3]};
      ui32x4 v1 = {cw[4], cw[5], cw[6], cw[7]};
      *(ui32x4*)&Al[s_a * 64 + ((c_a ^ sw_a) * 8)] = v0;
      *(ui32x4*)&Al[s_a * 64 + (((c_a + 4) ^ sw_a) * 8)] = v1;
    }
    __syncthreads();  // (b) A tile visible

    if (kt < 7) {
      const int ktn = kt + 1;
      // prefetch B(kt+1) into other buffer, A(kt+1) into regs
#pragma unroll
      for (int i = 0; i < 4; ++i) {
        int q = w * 4 + i;
        gl2lds16(Bb + (size_t)(q * 8 + brow) * 512 + ktn * 64 + bko,
                 &Bl[ktn & 1][q * 512]);
      }
#pragma unroll
      for (int j = 0; j < 8; ++j)
        pre[j] = apb[(size_t)(ktn * 64 + c_a * 8 + j) * 576];
#pragma unroll
      for (int j = 0; j < 8; ++j)
        pre[8 + j] = apb[(size_t)(ktn * 64 + c_a * 8 + 32 + j) * 576];
    }

    const u16* Blc = Bl[kt & 1];
#pragma unroll
    for (int hh = 0; hh < 2; ++hh) {
      s16x8 af[4], bfr[2];
#pragma unroll
      for (int mi = 0; mi < 4; ++mi) {
        int row = mi * 16 + llo;
        af[mi] = *(const s16x8*)&Al[row * 64 + ((((hh << 2) | lhi) ^ (row & 7)) * 8)];
      }
#pragma unroll
      for (int ni = 0; ni < 2; ++ni) {
        int n = w * 32 + ni * 16 + llo;
        bfr[ni] = *(const s16x8*)&Blc[n * 64 + ((((hh << 2) | lhi) ^ (n & 7)) * 8)];
      }
#pragma unroll
      for (int mi = 0; mi < 4; ++mi)
#pragma unroll
        for (int ni = 0; ni < 2; ++ni)
          acc[mi][ni] = __builtin_amdgcn_mfma_f32_16x16x32_bf16(
              af[mi], bfr[ni], acc[mi][ni], 0, 0, 0);
    }
  }

  const int b_ = bt >> 4, t_ = bt & 15;
  const size_t rowbase = (size_t)(b_ * 576 + s0) * 16 + t_;
  float bia0 = bias[col0 + w * 32 + llo];
  float bia1 = bias[col0 + w * 32 + 16 + llo];
#pragma unroll
  for (int mi = 0; mi < 4; ++mi) {
#pragma unroll
    for (int i = 0; i < 4; ++i) {
      const int m = mi * 16 + lhi * 4 + i;
      u16* cp = C + (rowbase + (size_t)m * 16) * NC + col0 + w * 32 + llo;
      cp[0]  = f2bf(acc[mi][0][i] + bia0);
      cp[16] = f2bf(acc[mi][1][i] + bia1);
    }
  }
}

// -------- penalty MLP tail: gelu -> dot(Wp2) -> sigmoid, one wave per row ----
__global__ __launch_bounds__(256) void pviol_kernel(
    const u16* __restrict__ KVP, const float* __restrict__ Wp2,
    const float* __restrict__ bp2, float* __restrict__ pv)
{
  const int tid = threadIdx.x;
  const int w = tid >> 6, lane = tid & 63;
  const int row = blockIdx.x * 4 + w;
  const int c = lane * 2;
  const u16* hp = KVP + (size_t)row * 1152 + 1024 + c;
  float x0 = b2f(hp[0]), x1 = b2f(hp[1]);
  float g0 = 0.5f * x0 * (1.f + erff(x0 * 0.70710678f));
  float g1 = 0.5f * x1 * (1.f + erff(x1 * 0.70710678f));
  float sum = g0 * Wp2[c] + g1 * Wp2[c + 1];
#pragma unroll
  for (int d = 1; d < 64; d <<= 1) sum += __shfl_xor(sum, d, 64);
  if (lane == 0) {
    float z = sum + bp2[0];
    pv[row] = 1.f / (1.f + expf(-z));
  }
}

// -------- attention: one wave per (n, head). att aliases Q (disjoint per wave).
__global__ __launch_bounds__(256) void attn_kernel(
    const u16* Q, const u16* __restrict__ KVP,
    const float* __restrict__ pviol, u16* att)
{
  __shared__ __align__(16) u16 Kl[4][16 * 72];
  __shared__ __align__(16) u16 Vl[4][16 * 72];
  __shared__ float Pl[4][16 * 17];
  const int tid = threadIdx.x;
  const int w = tid >> 6, lane = tid & 63;
  const int logical = xcd_swz(blockIdx.x, gridDim.x);
  const int wid = logical * 4 + w;
  const int n = wid >> 3, hh = wid & 7;
  const int g = lane >> 4, tq = lane & 15;

  const int r = lane >> 3, co = (lane & 7) * 8;
  const u16* Kb = KVP + (size_t)n * (16 * 1152) + hh * 64;
#pragma unroll
  for (int rr = 0; rr < 2; ++rr) {
    int row = r + rr * 8;
    *(u16x8*)&Kl[w][row * 72 + co] = *(const u16x8*)(Kb + row * 1152 + co);
    *(u16x8*)&Vl[w][row * 72 + co] = *(const u16x8*)(Kb + 512 + row * 1152 + co);
  }
  __syncthreads();

  float s[4] = {0.f, 0.f, 0.f, 0.f};
  const u16* Qr = Q + ((size_t)n * 16 + tq) * 512 + hh * 64;
  for (int kc = 0; kc < 8; ++kc) {
    u16x8 q8 = *(const u16x8*)(Qr + kc * 8);
    float qf[8];
#pragma unroll
    for (int j = 0; j < 8; ++j) qf[j] = b2f(q8[j]);
#pragma unroll
    for (int i = 0; i < 4; ++i) {
      u16x8 k8 = *(const u16x8*)&Kl[w][(g * 4 + i) * 72 + kc * 8];
#pragma unroll
      for (int j = 0; j < 8; ++j) s[i] += qf[j] * b2f(k8[j]);
    }
  }

  const float* pv = pviol + n * 16;
#pragma unroll
  for (int i = 0; i < 4; ++i) s[i] = s[i] * 0.125f - GAMMA * pv[g * 4 + i];

  float mx = fmaxf(fmaxf(s[0], s[1]), fmaxf(s[2], s[3]));
  mx = fmaxf(mx, __shfl_xor(mx, 16, 64));
  mx = fmaxf(mx, __shfl_xor(mx, 32, 64));
  float e[4], sum = 0.f;
#pragma unroll
  for (int i = 0; i < 4; ++i) { e[i] = expf(s[i] - mx); sum += e[i]; }
  sum += __shfl_xor(sum, 16, 64);
  sum += __shfl_xor(sum, 32, 64);
  float inv = 1.f / sum;
#pragma unroll
  for (int i = 0; i < 4; ++i) Pl[w][tq * 17 + g * 4 + i] = e[i] * inv;
  __syncthreads();

  float o[16];
#pragma unroll
  for (int j = 0; j < 16; ++j) o[j] = 0.f;
  for (int tk = 0; tk < 16; ++tk) {
    float p = Pl[w][tq * 17 + tk];
    u16x8 v0 = *(const u16x8*)&Vl[w][tk * 72 + g * 16];
    u16x8 v1 = *(const u16x8*)&Vl[w][tk * 72 + g * 16 + 8];
#pragma unroll
    for (int j = 0; j < 8; ++j) {
      o[j]     += p * b2f(v0[j]);
      o[8 + j] += p * b2f(v1[j]);
    }
  }
  u16* op = att + ((size_t)n * 16 + tq) * 512 + hh * 64 + g * 16;
  u16x8 r0, r1;
#pragma unroll
  for (int j = 0; j < 8; ++j) { r0[j] = f2bf(o[j]); r1[j] = f2bf(o[8 + j]); }
  *(u16x8*)op = r0;
  *(u16x8*)(op + 8) = r1;
}

// ---------------------------------------------------------------------------
// Output projection: bf16 A (row-major, stride 16*512) x WoT.
// BM=64 x BN=128 x BK=64, 8 K-steps, both operands double-buffered
// global_load_lds with pre-swizzled source; ONE barrier per K-step.
// ---------------------------------------------------------------------------
__global__ __launch_bounds__(256) void gemm_out(
    const u16* __restrict__ A, const u16* __restrict__ WT,
    const float* __restrict__ bias, float* __restrict__ out)
{
  __shared__ __align__(16) char smem[49152];       // Al(16K)+Bl(32K); Cl aliases
  u16* Al0 = (u16*)smem;                           // [2][64*64]
  u16* Bl0 = (u16*)(smem + 16384);                 // [2][128*64]
  const int tid = threadIdx.x;
  const int w = tid >> 6, lane = tid & 63;
  const int lhi = lane >> 4, llo = lane & 15;

  const int nwg = gridDim.x * gridDim.y;
  const int phys = blockIdx.y * gridDim.x + blockIdx.x;
  const int logical = xcd_swz(phys, nwg);
  const int bx = logical % gridDim.x;
  const int y = logical / gridDim.x;

  const int bt = y / 9, stile = y - bt * 9;
  const int s0 = stile * 64;
  const int col0 = bx * 128;
  const int b_ = bt >> 4, t_ = bt & 15;

  const u16* Ab = A + ((size_t)(b_ * 576 + s0) * 16 + t_) * 512;
  const u16* Bb = WT + (size_t)col0 * 512;

  const int brow = lane >> 3;
  const int bko = ((lane & 7) ^ brow) * 8;

  f32x4 acc[4][2];
#pragma unroll
  for (int mi = 0; mi < 4; ++mi)
#pragma unroll
    for (int ni = 0; ni < 2; ++ni)
#pragma unroll
      for (int e = 0; e < 4; ++e) acc[mi][ni][e] = 0.f;

  // prologue: stage tiles(0)
#pragma unroll
  for (int i = 0; i < 2; ++i) {
    int q = w * 2 + i;
    gl2lds16(Ab + (size_t)(q * 8 + brow) * (16 * 512) + bko, &Al0[q * 512]);
  }
#pragma unroll
  for (int i = 0; i < 4; ++i) {
    int q = w * 4 + i;
    gl2lds16(Bb + (size_t)(q * 8 + brow) * 512 + bko, &Bl0[q * 512]);
  }

  for (int kt = 0; kt < 8; ++kt) {
    __syncthreads();  // tiles(kt) resident; prev compute reads done
    if (kt < 7) {
      const int ktn = kt + 1;
      u16* Ala = Al0 + (ktn & 1) * (64 * 64);
      u16* Bla = Bl0 + (ktn & 1) * (128 * 64);
#pragma unroll
      for (int i = 0; i < 2; ++i) {
        int q = w * 2 + i;
        gl2lds16(Ab + (size_t)(q * 8 + brow) * (16 * 512) + ktn * 64 + bko,
                 &Ala[q * 512]);
      }
#pragma unroll
      for (int i = 0; i < 4; ++i) {
        int q = w * 4 + i;
        gl2lds16(Bb + (size_t)(q * 8 + brow) * 512 + ktn * 64 + bko,
                 &Bla[q * 512]);
      }
    }
    const u16* Alc = Al0 + (kt & 1) * (64 * 64);
    const u16* Blc = Bl0 + (kt & 1) * (128 * 64);
#pragma unroll
    for (int hh = 0; hh < 2; ++hh) {
      s16x8 af[4], bfr[2];
#pragma unroll
      for (int mi = 0; mi < 4; ++mi) {
        int row = mi * 16 + llo;
        af[mi] = *(const s16x8*)&Alc[row * 64 + ((((hh << 2) | lhi) ^ (row & 7)) * 8)];
      }
#pragma unroll
      for (int ni = 0; ni < 2; ++ni) {
        int n = w * 32 + ni * 16 + llo;
        bfr[ni] = *(const s16x8*)&Blc[n * 64 + ((((hh << 2) | lhi) ^ (n & 7)) * 8)];
      }
#pragma unroll
      for (int mi = 0; mi < 4; ++mi)
#pragma unroll
        for (int ni = 0; ni < 2; ++ni)
          acc[mi][ni] = __builtin_amdgcn_mfma_f32_16x16x32_bf16(
              af[mi], bfr[ni], acc[mi][ni], 0, 0, 0);
    }
  }

  __syncthreads();
  float* Cl = (float*)smem;  // 128 (n) x 72 (m, padded) fp32
  float bia0 = bias[col0 + w * 32 + llo];
  float bia1 = bias[col0 + w * 32 + 16 + llo];
#pragma unroll
  for (int mi = 0; mi < 4; ++mi)
#pragma unroll
    for (int i = 0; i < 4; ++i) {
      int m = mi * 16 + lhi * 4 + i;
      Cl[(w * 32 + llo) * 72 + m]      = acc[mi][0][i] + bia0;
      Cl[(w * 32 + 16 + llo) * 72 + m] = acc[mi][1][i] + bia1;
    }
  __syncthreads();
  const int nn = tid >> 1;
  const int mh = (tid & 1) * 32;
  const float* sp = Cl + nn * 72 + mh;
  float* dp = out + ((size_t)bt * 512 + col0 + nn) * 576 + s0 + mh;
#pragma unroll
  for (int j = 0; j < 8; ++j)
    *(float4*)(dp + j * 4) = *(const float4*)(sp + j * 4);
}

extern "C" void kernel_launch(void* const* d_in, const int* in_sizes, int n_in,
                              void* d_out, int out_size, void* d_ws, size_t ws_size,
                              hipStream_t stream)
{
  const float* h_opt = (const float*)d_in[0];
  const float* h_sar = (const float*)d_in[1];
  const float* Wq  = (const float*)d_in[2];
  const float* bq  = (const float*)d_in[3];
  const float* Wk  = (const float*)d_in[4];
  const float* bk  = (const float*)d_in[5];
  const float* Wv  = (const float*)d_in[6];
  const float* bv  = (const float*)d_in[7];
  const float* Wo  = (const float*)d_in[8];
  const float* bo  = (const float*)d_in[9];
  const float* Wp1 = (const float*)d_in[10];
  const float* bp1 = (const float*)d_in[11];
  const float* Wp2 = (const float*)d_in[12];
  const float* bp2 = (const float*)d_in[13];
  float* out = (float*)d_out;

  char* ws = (char*)d_ws;
  u16*   WqT     = (u16*)(ws + 0);          // 512x512 bf16   (524288 B)
  u16*   KVPW    = (u16*)(ws + 524288);     // 1152x512 bf16  (1179648 B)
  u16*   WoT     = (u16*)(ws + 1703936);    // 512x512 bf16   (524288 B)
  float* biasQ   = (float*)(ws + 2228224);  // 512 f32
  float* biasKVP = (float*)(ws + 2230272);  // 1152 f32
  float* biasO   = (float*)(ws + 2234880);  // 512 f32
  float* pviol   = (float*)(ws + 2236928);  // 36864 f32
  u16*   Qbuf    = (u16*)(ws + 2384384);    // 36864x512 bf16  — also att
  u16*   KVPbuf  = (u16*)(ws + 40133120);   // 36864x1152 bf16

  transpose_k<<<1024, 256, 0, stream>>>(Wq, WqT, 512, 512);
  transpose_k<<<1024, 256, 0, stream>>>(Wk, KVPW, 512, 512);
  transpose_k<<<1024, 256, 0, stream>>>(Wv, KVPW + 512 * 512, 512, 512);
  transpose_k<<<256, 256, 0, stream>>>(Wp1, KVPW + 1024 * 512, 512, 128);
  transpose_k<<<1024, 256, 0, stream>>>(Wo, WoT, 512, 512);
  bias_kernel<<<9, 256, 0, stream>>>(bq, bk, bv, bp1, bo, biasQ, biasKVP, biasO);

  gemm_gather<<<dim3(4, 576), 256, 0, stream>>>(h_opt, WqT, biasQ, Qbuf, 512);
  gemm_gather<<<dim3(9, 576), 256, 0, stream>>>(h_sar, KVPW, biasKVP, KVPbuf, 1152);
  pviol_kernel<<<9216, 256, 0, stream>>>(KVPbuf, Wp2, bp2, pviol);
  attn_kernel<<<4608, 256, 0, stream>>>(Qbuf, KVPbuf, pviol, Qbuf);
  gemm_out<<<dim3(4, 576), 256, 0, stream>>>(Qbuf, WoT, biasO, out);
}